// Round 1
// 961.180 us; speedup vs baseline: 1.1286x; 1.1286x over previous
//
#include <hip/hip_runtime.h>
#include <hip/hip_bf16.h>
#include <math.h>

typedef __hip_bfloat16 bf16;
typedef __hip_bfloat162 bf162;
typedef __attribute__((ext_vector_type(8))) short bf16x8;   // MFMA A/B frag (4 VGPRs)
typedef __attribute__((ext_vector_type(4))) short short4v;  // 8B store
typedef __attribute__((ext_vector_type(4))) float f32x4;    // MFMA C/D frag

__device__ __forceinline__ float b2f(bf16 x){ return __bfloat162float(x); }
__device__ __forceinline__ bf16  f2b(float x){ return __float2bfloat16(x); }
__device__ __forceinline__ short f2bs(float x){ bf16 h = __float2bfloat16(x); return *(short*)&h; }

constexpr int kH = 112, kW = 112, kC = 128, kHeads = 4, kWS = 7;
constexpr int kN = 49, kHD = 32, kL = kH * kW;      // L = 12544
constexpr int kWinElems = kN * kC;                  // 6272
constexpr int kMLP = 512;
constexpr float kEps = 1e-5f;
constexpr float kScale = 0.17677669529663687f;      // 1/sqrt(32)
constexpr int kAP = 136;      // LDS row stride (bf16): 272B = 17*16
constexpr int kHP = 520;      // MLP hidden stride

// ---------------------------------------------------------------------------
// K0: convert all weight matrices fp32 -> bf16 into one ws arena.
// Layout: [qwb 16384 | kvwb 32768 | pwb 16384 | w1b 65536 | w2b 65536]
__global__ __launch_bounds__(256) void k_cvt(
    const float* __restrict__ qw, const float* __restrict__ kvw,
    const float* __restrict__ pw, const float* __restrict__ w1,
    const float* __restrict__ w2, short* __restrict__ dst)
{
    const int i = blockIdx.x * 256 + threadIdx.x;   // 196608 total
    float val;
    if (i < 16384)       val = qw[i];
    else if (i < 49152)  val = kvw[i - 16384];
    else if (i < 65536)  val = pw[i - 49152];
    else if (i < 131072) val = w1[i - 65536];
    else                 val = w2[i - 131072];
    dst[i] = f2bs(val);
}

// ---------------------------------------------------------------------------
// K1 (MFMA): LN(x), LN(v) + Q/K/V projection + window-partition scatter.
// 32 consecutive (b,l) rows per block; weights = A operand, acts = B operand.
// D layout: col(lane&15)=row m, row(quad*4+i)=out channel -> 8B bf16x4 stores.
__global__ __launch_bounds__(256) void k_ln_qkv_mfma(
    const float* __restrict__ x, const float* __restrict__ v,
    const float* __restrict__ n1g, const float* __restrict__ n1b,
    const float* __restrict__ nvg, const float* __restrict__ nvb,
    const short* __restrict__ qwb, const float* __restrict__ qb,
    const short* __restrict__ kvwb, const float* __restrict__ kvb,
    bf16* __restrict__ qo, bf16* __restrict__ ko, bf16* __restrict__ vo)
{
    __shared__ short Xs[32 * kAP], Vs[32 * kAP];
    const int tid = threadIdx.x, wave = tid >> 6, lane = tid & 63;
    const int quad = lane >> 4, l16 = lane & 15;
    const int row0 = blockIdx.x * 32;
    const int c0 = lane * 2;

    // ---- LN(x), LN(v) -> LDS bf16 ----
    for (int n = wave; n < 32; n += 4) {
        const size_t r = (size_t)(row0 + n) * kC;
        const float2 xv = *(const float2*)(x + r + c0);
        const float2 vv = *(const float2*)(v + r + c0);
        float sx = xv.x + xv.y, qx = xv.x * xv.x + xv.y * xv.y;
        float sv = vv.x + vv.y, qv = vv.x * vv.x + vv.y * vv.y;
        #pragma unroll
        for (int off = 32; off > 0; off >>= 1) {
            sx += __shfl_xor(sx, off); qx += __shfl_xor(qx, off);
            sv += __shfl_xor(sv, off); qv += __shfl_xor(qv, off);
        }
        const float mux = sx * (1.f / kC);
        const float ivx = rsqrtf(qx * (1.f / kC) - mux * mux + kEps);
        const float muv = sv * (1.f / kC);
        const float ivv = rsqrtf(qv * (1.f / kC) - muv * muv + kEps);
        Xs[n * kAP + c0]     = f2bs((xv.x - mux) * ivx * n1g[c0] + n1b[c0]);
        Xs[n * kAP + c0 + 1] = f2bs((xv.y - mux) * ivx * n1g[c0 + 1] + n1b[c0 + 1]);
        Vs[n * kAP + c0]     = f2bs((vv.x - muv) * ivv * nvg[c0] + nvb[c0]);
        Vs[n * kAP + c0 + 1] = f2bs((vv.y - muv) * ivv * nvg[c0 + 1] + nvb[c0 + 1]);
    }
    __syncthreads();

    // ---- windowed scatter offsets for this lane's two m-tile rows ----
    int woff[2];
    #pragma unroll
    for (int mt = 0; mt < 2; mt++) {
        const int gr = row0 + mt * 16 + l16;
        const int b = gr / kL, l = gr - b * kL;
        const int h = l / kW, w_ = l - h * kW;
        woff[mt] = ((b << 8) + (h / 7) * 16 + (w_ / 7)) * kWinElems
                 + ((h % 7) * 7 + (w_ % 7)) * kC;
    }

    // ---- preload activation B-fragments ----
    bf16x8 xf[2][4], vf[2][4];
    #pragma unroll
    for (int mt = 0; mt < 2; mt++)
        #pragma unroll
        for (int ks = 0; ks < 4; ks++) {
            xf[mt][ks] = *(const bf16x8*)&Xs[(mt * 16 + l16) * kAP + ks * 32 + quad * 8];
            vf[mt][ks] = *(const bf16x8*)&Vs[(mt * 16 + l16) * kAP + ks * 32 + quad * 8];
        }

    // ---- 24 out-channel tiles (q:0-7, k:8-15, v:16-23), 6 per wave ----
    #pragma unroll
    for (int j = 0; j < 6; j++) {
        const int nt = wave * 6 + j;
        const bool isq = (nt < 8);
        const short* wmat = isq ? qwb : kvwb;
        const int wr0 = (isq ? nt : nt - 8) * 16;
        const float* bias = isq ? qb : kvb;
        const int bidx = wr0 + quad * 4;
        f32x4 a0 = { bias[bidx], bias[bidx + 1], bias[bidx + 2], bias[bidx + 3] };
        f32x4 a1 = a0;
        if (isq) {
            #pragma unroll
            for (int ks = 0; ks < 4; ks++) {
                const bf16x8 af = *(const bf16x8*)(wmat + (size_t)(wr0 + l16) * kC + ks * 32 + quad * 8);
                a0 = __builtin_amdgcn_mfma_f32_16x16x32_bf16(af, xf[0][ks], a0, 0, 0, 0);
                a1 = __builtin_amdgcn_mfma_f32_16x16x32_bf16(af, xf[1][ks], a1, 0, 0, 0);
            }
        } else {
            #pragma unroll
            for (int ks = 0; ks < 4; ks++) {
                const bf16x8 af = *(const bf16x8*)(wmat + (size_t)(wr0 + l16) * kC + ks * 32 + quad * 8);
                a0 = __builtin_amdgcn_mfma_f32_16x16x32_bf16(af, vf[0][ks], a0, 0, 0, 0);
                a1 = __builtin_amdgcn_mfma_f32_16x16x32_bf16(af, vf[1][ks], a1, 0, 0, 0);
            }
        }
        bf16* dst = isq ? qo : (nt < 16 ? ko : vo);
        const int cb = (isq ? nt : (nt < 16 ? nt - 8 : nt - 16)) * 16 + quad * 4;
        short4v p0, p1;
        #pragma unroll
        for (int i = 0; i < 4; i++) { p0[i] = f2bs(a0[i]); p1[i] = f2bs(a1[i]); }
        *(short4v*)((short*)dst + (size_t)woff[0] + cb) = p0;
        *(short4v*)((short*)dst + (size_t)woff[1] + cb) = p1;
    }
}

// ---------------------------------------------------------------------------
// K2: attention per (window, head). Writes back over the q buffer.
__global__ __launch_bounds__(256) void k_attn(
    bf16* __restrict__ qbuf, const bf16* __restrict__ kbuf,
    const bf16* __restrict__ vbuf, const float* __restrict__ rpb)
{
    __shared__ float qs[kN][kHD + 1], ks[kN][kHD + 1], vs[kN][kHD + 1];
    __shared__ float S[kN][kN + 1];
    const int wb = blockIdx.x, head = blockIdx.y;
    const int tid = threadIdx.x;
    const size_t base = (size_t)wb * kWinElems + head * kHD;
    for (int i = tid; i < kN * kHD; i += 256) {
        const int n = i >> 5, d = i & 31;
        qs[n][d] = b2f(qbuf[base + (size_t)n * kC + d]);
        ks[n][d] = b2f(kbuf[base + (size_t)n * kC + d]);
        vs[n][d] = b2f(vbuf[base + (size_t)n * kC + d]);
    }
    __syncthreads();
    for (int i = tid; i < kN * kN; i += 256) {
        const int n = i / 49, m = i % 49;
        float acc = 0.f;
        #pragma unroll
        for (int d = 0; d < kHD; d++) acc += qs[n][d] * ks[m][d];
        const int ry = n / 7 - m / 7 + 6, rx = n % 7 - m % 7 + 6;
        S[n][m] = acc * kScale + rpb[(ry * 13 + rx) * kHeads + head];
    }
    __syncthreads();
    if (tid < kN) {
        float mx = -1e30f;
        for (int m = 0; m < kN; m++) mx = fmaxf(mx, S[tid][m]);
        float sum = 0.f;
        for (int m = 0; m < kN; m++) { const float e = __expf(S[tid][m] - mx); S[tid][m] = e; sum += e; }
        const float inv = 1.f / sum;
        for (int m = 0; m < kN; m++) S[tid][m] *= inv;
    }
    __syncthreads();
    for (int i = tid; i < kN * kHD; i += 256) {
        const int n = i >> 5, d = i & 31;
        float acc = 0.f;
        for (int m = 0; m < kN; m++) acc += S[n][m] * vs[m][d];
        qbuf[base + (size_t)n * kC + d] = f2b(acc);
    }
}

// ---------------------------------------------------------------------------
// K3 (MFMA): window-reverse gather + output projection + residual -> d_out.
__global__ __launch_bounds__(256) void k_proj_mfma(
    const bf16* __restrict__ ao, const short* __restrict__ pwb,
    const float* __restrict__ pb, const float* __restrict__ x,
    float* __restrict__ out)
{
    __shared__ short As[32 * kAP];
    const int tid = threadIdx.x, wave = tid >> 6, lane = tid & 63;
    const int quad = lane >> 4, l16 = lane & 15;
    const int row0 = blockIdx.x * 32;
    const int c0 = lane * 2;

    // gather windowed attn rows into LDS (bf16 passthrough)
    for (int n = wave; n < 32; n += 4) {
        const int gr = row0 + n;
        const int b = gr / kL, l = gr - b * kL;
        const int h = l / kW, w_ = l - h * kW;
        const size_t off = (size_t)(((b << 8) + (h / 7) * 16 + (w_ / 7))) * kWinElems
                         + ((h % 7) * 7 + (w_ % 7)) * kC;
        *(int*)&As[n * kAP + c0] = *(const int*)((const short*)ao + off + c0);
    }
    __syncthreads();

    bf16x8 bfrag[2][4];
    #pragma unroll
    for (int mt = 0; mt < 2; mt++)
        #pragma unroll
        for (int ks = 0; ks < 4; ks++)
            bfrag[mt][ks] = *(const bf16x8*)&As[(mt * 16 + l16) * kAP + ks * 32 + quad * 8];

    #pragma unroll
    for (int j = 0; j < 2; j++) {
        const int nt = wave * 2 + j;
        const int cb = nt * 16 + quad * 4;
        f32x4 a0 = { pb[cb], pb[cb + 1], pb[cb + 2], pb[cb + 3] };
        f32x4 a1 = a0;
        #pragma unroll
        for (int ks = 0; ks < 4; ks++) {
            const bf16x8 af = *(const bf16x8*)(pwb + (size_t)(nt * 16 + l16) * kC + ks * 32 + quad * 8);
            a0 = __builtin_amdgcn_mfma_f32_16x16x32_bf16(af, bfrag[0][ks], a0, 0, 0, 0);
            a1 = __builtin_amdgcn_mfma_f32_16x16x32_bf16(af, bfrag[1][ks], a1, 0, 0, 0);
        }
        #pragma unroll
        for (int mt = 0; mt < 2; mt++) {
            const size_t gr = row0 + mt * 16 + l16;
            float4 res = *(const float4*)(x + gr * kC + cb);
            const f32x4 a = mt ? a1 : a0;
            res.x += a[0]; res.y += a[1]; res.z += a[2]; res.w += a[3];
            *(float4*)(out + gr * kC + cb) = res;
        }
    }
}

// ---------------------------------------------------------------------------
// K4 (MFMA): LN2 + fc1 + exact GELU + fc2 + residual, in-place on d_out.
// Rewritten for latency hiding: A_s/H_s LDS union (33280 B -> 4 blocks/CU),
// batched LN loads + interleaved shuffle reductions, depth-1 weight prefetch
// in fc1/fc2, fc2 split so w2 is read once per block.
constexpr int kMT = 32;

__global__ __launch_bounds__(256, 4) void k_mlp_mfma(
    float* __restrict__ out,
    const float* __restrict__ g2, const float* __restrict__ b2v,
    const short* __restrict__ w1b, const float* __restrict__ bb1,
    const short* __restrict__ w2b, const float* __restrict__ bb2)
{
    // Union arena: A_s (32 x kAP = 4352 shorts) lives only until the B-frags
    // are preloaded to registers; H_s (32 x kHP = 16640 shorts) then reuses it.
    __shared__ short LDSu[kMT * kHP];            // 33280 B
    short* const A_s = LDSu;
    short* const H_s = LDSu;
    const int tid = threadIdx.x, wave = tid >> 6, lane = tid & 63;
    const int quad = lane >> 4, l16 = lane & 15;
    const size_t row0 = (size_t)blockIdx.x * kMT;
    const int c0 = lane * 2;

    // ---- LN2: batch all 8 row loads, run 8 reduction chains interleaved ----
    const float gg0 = g2[c0], gg1 = g2[c0 + 1];
    const float bv0 = b2v[c0], bv1 = b2v[c0 + 1];
    float2 xv[8];
    #pragma unroll
    for (int it = 0; it < 8; it++)
        xv[it] = *(const float2*)(out + (row0 + wave + it * 4) * kC + c0);
    float s[8], q[8];
    #pragma unroll
    for (int it = 0; it < 8; it++) {
        s[it] = xv[it].x + xv[it].y;
        q[it] = xv[it].x * xv[it].x + xv[it].y * xv[it].y;
    }
    #pragma unroll
    for (int off = 32; off > 0; off >>= 1) {
        #pragma unroll
        for (int it = 0; it < 8; it++) {
            s[it] += __shfl_xor(s[it], off);
            q[it] += __shfl_xor(q[it], off);
        }
    }
    #pragma unroll
    for (int it = 0; it < 8; it++) {
        const int n = wave + it * 4;
        const float mu = s[it] * (1.f / kC);
        const float iv = rsqrtf(q[it] * (1.f / kC) - mu * mu + kEps);
        const short h0 = f2bs((xv[it].x - mu) * iv * gg0 + bv0);
        const short h1 = f2bs((xv[it].y - mu) * iv * gg1 + bv1);
        *(int*)&A_s[n * kAP + c0] =
            ((int)(unsigned short)h1 << 16) | (int)(unsigned short)h0;
    }
    __syncthreads();

    // ---- preload activation B-fragments; A_s dead afterwards ----
    bf16x8 bfrag[2][4];
    #pragma unroll
    for (int mt = 0; mt < 2; mt++)
        #pragma unroll
        for (int ks = 0; ks < 4; ks++)
            bfrag[mt][ks] = *(const bf16x8*)&A_s[(mt * 16 + l16) * kAP + ks * 32 + quad * 8];
    __syncthreads();    // everyone's bfrag done before H_s overwrites the arena

    // ---- fc1 + GELU: 8 n-tiles/wave in 2 groups of 4, weight prefetch ----
    const short* wbase = w1b + (size_t)(wave * 128 + l16) * kC + quad * 8;
    auto loadw1 = [&](bf16x8* dst, int t) {
        #pragma unroll
        for (int ks = 0; ks < 4; ks++)
            dst[ks] = *(const bf16x8*)(wbase + (size_t)t * (16 * kC) + ks * 32);
    };
    auto mfma8 = [&](f32x4* a, const bf16x8* w) {
        #pragma unroll
        for (int ks = 0; ks < 4; ks++) {
            a[0] = __builtin_amdgcn_mfma_f32_16x16x32_bf16(w[ks], bfrag[0][ks], a[0], 0, 0, 0);
            a[1] = __builtin_amdgcn_mfma_f32_16x16x32_bf16(w[ks], bfrag[1][ks], a[1], 0, 0, 0);
        }
    };
    #pragma unroll
    for (int g = 0; g < 2; g++) {
        f32x4 acc[4][2];
        #pragma unroll
        for (int t = 0; t < 4; t++) {
            const float4 bi = *(const float4*)(bb1 + (wave * 8 + g * 4 + t) * 16 + quad * 4);
            acc[t][0] = (f32x4){ bi.x, bi.y, bi.z, bi.w };
            acc[t][1] = acc[t][0];
        }
        bf16x8 wA[4], wB[4];
        loadw1(wA, g * 4 + 0);
        loadw1(wB, g * 4 + 1);      // depth-1 prefetch
        mfma8(acc[0], wA);
        loadw1(wA, g * 4 + 2);
        mfma8(acc[1], wB);
        loadw1(wB, g * 4 + 3);
        mfma8(acc[2], wA);
        mfma8(acc[3], wB);
        // exact GELU + store hidden tile to LDS (bf16)
        #pragma unroll
        for (int t = 0; t < 4; t++) {
            const int nb = (wave * 8 + g * 4 + t) * 16 + quad * 4;
            #pragma unroll
            for (int mt = 0; mt < 2; mt++) {
                short4v p;
                #pragma unroll
                for (int i = 0; i < 4; i++) {
                    const float a = acc[t][mt][i];
                    p[i] = f2bs(0.5f * a * (1.f + erff(a * 0.70710678118f)));
                }
                *(short4v*)&H_s[(mt * 16 + l16) * kHP + nb] = p;
            }
        }
    }
    __syncthreads();

    // ---- fc2: wave owns out-tiles ct0, ct0+1 for BOTH m-tiles ----
    // (w2 read once per block; H re-read from LDS is cheap)
    const int ct0 = wave * 2;
    f32x4 acc2[2][2];   // [tile][mt]
    #pragma unroll
    for (int t = 0; t < 2; t++) {
        const float4 bi = *(const float4*)(bb2 + (ct0 + t) * 16 + quad * 4);
        acc2[t][0] = (f32x4){ bi.x, bi.y, bi.z, bi.w };
        acc2[t][1] = acc2[t][0];
    }
    const short* w2base = w2b + (size_t)(ct0 * 16 + l16) * kMLP + quad * 8;
    const short* hbase0 = &H_s[l16 * kHP + quad * 8];          // mt = 0
    const short* hbase1 = &H_s[(16 + l16) * kHP + quad * 8];   // mt = 1
    auto loadh = [&](bf16x8* h, bf16x8* w, int kk) {
        h[0] = *(const bf16x8*)(hbase0 + kk * 32);
        h[1] = *(const bf16x8*)(hbase1 + kk * 32);
        w[0] = *(const bf16x8*)(w2base + kk * 32);
        w[1] = *(const bf16x8*)(w2base + (size_t)16 * kMLP + kk * 32);
    };
    auto mfma4 = [&](const bf16x8* h, const bf16x8* w) {
        acc2[0][0] = __builtin_amdgcn_mfma_f32_16x16x32_bf16(w[0], h[0], acc2[0][0], 0, 0, 0);
        acc2[0][1] = __builtin_amdgcn_mfma_f32_16x16x32_bf16(w[0], h[1], acc2[0][1], 0, 0, 0);
        acc2[1][0] = __builtin_amdgcn_mfma_f32_16x16x32_bf16(w[1], h[0], acc2[1][0], 0, 0, 0);
        acc2[1][1] = __builtin_amdgcn_mfma_f32_16x16x32_bf16(w[1], h[1], acc2[1][1], 0, 0, 0);
    };
    bf16x8 hA[2], wwA[2], hB[2], wwB[2];
    loadh(hA, wwA, 0);
    #pragma unroll
    for (int kk = 0; kk < 16; kk += 2) {
        loadh(hB, wwB, kk + 1);     // depth-1 prefetch
        mfma4(hA, wwA);
        if (kk + 2 < 16) loadh(hA, wwA, kk + 2);
        mfma4(hB, wwB);
    }

    // ---- residual add + writeback ----
    #pragma unroll
    for (int t = 0; t < 2; t++) {
        const int cbv = (ct0 + t) * 16 + quad * 4;
        #pragma unroll
        for (int mt = 0; mt < 2; mt++) {
            const size_t m = row0 + mt * 16 + l16;
            float4 res = *(const float4*)(out + m * kC + cbv);
            res.x += acc2[t][mt][0]; res.y += acc2[t][mt][1];
            res.z += acc2[t][mt][2]; res.w += acc2[t][mt][3];
            *(float4*)(out + m * kC + cbv) = res;
        }
    }
}

// ---------------------------------------------------------------------------
extern "C" void kernel_launch(void* const* d_in, const int* in_sizes, int n_in,
                              void* d_out, int out_size, void* d_ws, size_t ws_size,
                              hipStream_t stream) {
    (void)in_sizes; (void)n_in; (void)out_size; (void)ws_size;
    const float* x      = (const float*)d_in[0];
    const float* v      = (const float*)d_in[1];
    const float* n1g    = (const float*)d_in[2];
    const float* n1b    = (const float*)d_in[3];
    const float* nvg    = (const float*)d_in[4];
    const float* nvb    = (const float*)d_in[5];
    const float* q_w    = (const float*)d_in[6];
    const float* q_b    = (const float*)d_in[7];
    const float* kv_w   = (const float*)d_in[8];
    const float* kv_b   = (const float*)d_in[9];
    const float* rpb    = (const float*)d_in[10];
    const float* proj_w = (const float*)d_in[11];
    const float* proj_b = (const float*)d_in[12];
    const float* n2g    = (const float*)d_in[13];
    const float* n2b    = (const float*)d_in[14];
    const float* fc1_w  = (const float*)d_in[15];
    const float* fc1_b  = (const float*)d_in[16];
    const float* fc2_w  = (const float*)d_in[17];
    const float* fc2_b  = (const float*)d_in[18];

    const size_t winTot = (size_t)4096 * kWinElems;   // 25,690,112 elems
    bf16* qbuf = (bf16*)d_ws;
    bf16* kbuf = qbuf + winTot;
    bf16* vbuf = kbuf + winTot;                        // 154 MB
    short* wcvt = (short*)(vbuf + winTot);             // bf16 weight arena
    short* qwb  = wcvt;                                // 16384
    short* kvwb = qwb + 16384;                         // 32768
    short* pwb  = kvwb + 32768;                        // 16384
    short* w1b  = pwb + 16384;                         // 65536
    short* w2b  = w1b + 65536;                         // 65536
    float* outb = (float*)d_out;

    k_cvt<<<768, 256, 0, stream>>>(q_w, kv_w, proj_w, fc1_w, fc2_w, wcvt);
    k_ln_qkv_mfma<<<6272, 256, 0, stream>>>(x, v, n1g, n1b, nvg, nvb,
                                            qwb, q_b, kvwb, kv_b, qbuf, kbuf, vbuf);
    k_attn<<<dim3(4096, 4), 256, 0, stream>>>(qbuf, kbuf, vbuf, rpb);
    k_proj_mfma<<<6272, 256, 0, stream>>>(qbuf, pwb, proj_b, x, outb);
    k_mlp_mfma<<<6272, 256, 0, stream>>>(outb, n2g, n2b, w1b, fc1_b, w2b, fc2_b);
}

// Round 2
// 746.794 us; speedup vs baseline: 1.4527x; 1.2871x over previous
//
#include <hip/hip_runtime.h>
#include <hip/hip_bf16.h>
#include <math.h>

typedef __hip_bfloat16 bf16;
typedef __hip_bfloat162 bf162;
typedef __attribute__((ext_vector_type(8))) short bf16x8;   // MFMA A/B frag (4 VGPRs)
typedef __attribute__((ext_vector_type(4))) short short4v;  // 8B store
typedef __attribute__((ext_vector_type(4))) float f32x4;    // MFMA C/D frag

__device__ __forceinline__ float b2f(bf16 x){ return __bfloat162float(x); }
__device__ __forceinline__ bf16  f2b(float x){ return __float2bfloat16(x); }
__device__ __forceinline__ short f2bs(float x){ bf16 h = __float2bfloat16(x); return *(short*)&h; }

constexpr int kH = 112, kW = 112, kC = 128, kHeads = 4, kWS = 7;
constexpr int kN = 49, kHD = 32, kL = kH * kW;      // L = 12544
constexpr int kWinElems = kN * kC;                  // 6272
constexpr int kMLP = 512;
constexpr float kEps = 1e-5f;
constexpr float kScale = 0.17677669529663687f;      // 1/sqrt(32)
constexpr int kAP = 136;      // LDS row stride (bf16): 272B = 17*16
constexpr int kHP = 520;      // MLP hidden stride

// ---------------------------------------------------------------------------
// K0: convert all weight matrices fp32 -> bf16 into one ws arena.
__global__ __launch_bounds__(256) void k_cvt(
    const float* __restrict__ qw, const float* __restrict__ kvw,
    const float* __restrict__ pw, const float* __restrict__ w1,
    const float* __restrict__ w2, short* __restrict__ dst)
{
    const int i = blockIdx.x * 256 + threadIdx.x;   // 196608 total
    float val;
    if (i < 16384)       val = qw[i];
    else if (i < 49152)  val = kvw[i - 16384];
    else if (i < 65536)  val = pw[i - 49152];
    else if (i < 131072) val = w1[i - 65536];
    else                 val = w2[i - 131072];
    dst[i] = f2bs(val);
}

// ---------------------------------------------------------------------------
// K1 (MFMA): LN(x), LN(v) + Q/K/V projection + window-partition scatter.
__global__ __launch_bounds__(256) void k_ln_qkv_mfma(
    const float* __restrict__ x, const float* __restrict__ v,
    const float* __restrict__ n1g, const float* __restrict__ n1b,
    const float* __restrict__ nvg, const float* __restrict__ nvb,
    const short* __restrict__ qwb, const float* __restrict__ qb,
    const short* __restrict__ kvwb, const float* __restrict__ kvb,
    bf16* __restrict__ qo, bf16* __restrict__ ko, bf16* __restrict__ vo)
{
    __shared__ short Xs[32 * kAP], Vs[32 * kAP];
    const int tid = threadIdx.x, wave = tid >> 6, lane = tid & 63;
    const int quad = lane >> 4, l16 = lane & 15;
    const int row0 = blockIdx.x * 32;
    const int c0 = lane * 2;

    for (int n = wave; n < 32; n += 4) {
        const size_t r = (size_t)(row0 + n) * kC;
        const float2 xv = *(const float2*)(x + r + c0);
        const float2 vv = *(const float2*)(v + r + c0);
        float sx = xv.x + xv.y, qx = xv.x * xv.x + xv.y * xv.y;
        float sv = vv.x + vv.y, qv = vv.x * vv.x + vv.y * vv.y;
        #pragma unroll
        for (int off = 32; off > 0; off >>= 1) {
            sx += __shfl_xor(sx, off); qx += __shfl_xor(qx, off);
            sv += __shfl_xor(sv, off); qv += __shfl_xor(qv, off);
        }
        const float mux = sx * (1.f / kC);
        const float ivx = rsqrtf(qx * (1.f / kC) - mux * mux + kEps);
        const float muv = sv * (1.f / kC);
        const float ivv = rsqrtf(qv * (1.f / kC) - muv * muv + kEps);
        Xs[n * kAP + c0]     = f2bs((xv.x - mux) * ivx * n1g[c0] + n1b[c0]);
        Xs[n * kAP + c0 + 1] = f2bs((xv.y - mux) * ivx * n1g[c0 + 1] + n1b[c0 + 1]);
        Vs[n * kAP + c0]     = f2bs((vv.x - muv) * ivv * nvg[c0] + nvb[c0]);
        Vs[n * kAP + c0 + 1] = f2bs((vv.y - muv) * ivv * nvg[c0 + 1] + nvb[c0 + 1]);
    }
    __syncthreads();

    int woff[2];
    #pragma unroll
    for (int mt = 0; mt < 2; mt++) {
        const int gr = row0 + mt * 16 + l16;
        const int b = gr / kL, l = gr - b * kL;
        const int h = l / kW, w_ = l - h * kW;
        woff[mt] = ((b << 8) + (h / 7) * 16 + (w_ / 7)) * kWinElems
                 + ((h % 7) * 7 + (w_ % 7)) * kC;
    }

    bf16x8 xf[2][4], vf[2][4];
    #pragma unroll
    for (int mt = 0; mt < 2; mt++)
        #pragma unroll
        for (int ks = 0; ks < 4; ks++) {
            xf[mt][ks] = *(const bf16x8*)&Xs[(mt * 16 + l16) * kAP + ks * 32 + quad * 8];
            vf[mt][ks] = *(const bf16x8*)&Vs[(mt * 16 + l16) * kAP + ks * 32 + quad * 8];
        }

    #pragma unroll
    for (int j = 0; j < 6; j++) {
        const int nt = wave * 6 + j;
        const bool isq = (nt < 8);
        const short* wmat = isq ? qwb : kvwb;
        const int wr0 = (isq ? nt : nt - 8) * 16;
        const float* bias = isq ? qb : kvb;
        const int bidx = wr0 + quad * 4;
        f32x4 a0 = { bias[bidx], bias[bidx + 1], bias[bidx + 2], bias[bidx + 3] };
        f32x4 a1 = a0;
        if (isq) {
            #pragma unroll
            for (int ks = 0; ks < 4; ks++) {
                const bf16x8 af = *(const bf16x8*)(wmat + (size_t)(wr0 + l16) * kC + ks * 32 + quad * 8);
                a0 = __builtin_amdgcn_mfma_f32_16x16x32_bf16(af, xf[0][ks], a0, 0, 0, 0);
                a1 = __builtin_amdgcn_mfma_f32_16x16x32_bf16(af, xf[1][ks], a1, 0, 0, 0);
            }
        } else {
            #pragma unroll
            for (int ks = 0; ks < 4; ks++) {
                const bf16x8 af = *(const bf16x8*)(wmat + (size_t)(wr0 + l16) * kC + ks * 32 + quad * 8);
                a0 = __builtin_amdgcn_mfma_f32_16x16x32_bf16(af, vf[0][ks], a0, 0, 0, 0);
                a1 = __builtin_amdgcn_mfma_f32_16x16x32_bf16(af, vf[1][ks], a1, 0, 0, 0);
            }
        }
        bf16* dst = isq ? qo : (nt < 16 ? ko : vo);
        const int cb = (isq ? nt : (nt < 16 ? nt - 8 : nt - 16)) * 16 + quad * 4;
        short4v p0, p1;
        #pragma unroll
        for (int i = 0; i < 4; i++) { p0[i] = f2bs(a0[i]); p1[i] = f2bs(a1[i]); }
        *(short4v*)((short*)dst + (size_t)woff[0] + cb) = p0;
        *(short4v*)((short*)dst + (size_t)woff[1] + cb) = p1;
    }
}

// ---------------------------------------------------------------------------
// K2 (MFMA): attention per window; wave = head. S=QK^T via MFMA (K=32 in one
// k-step), wave-parallel softmax in registers, PV via MFMA with V^T and P
// staged in XOR-swizzled LDS (T2: linear stride-64 would be 16-way conflict).
__global__ __launch_bounds__(256, 3) void k_attn_mfma(
    bf16* __restrict__ qbuf, const bf16* __restrict__ kbuf,
    const bf16* __restrict__ vbuf, const float* __restrict__ rpb)
{
    __shared__ short Pl[kHeads][64 * 64];   // P[n][m] bf16, swizzled (32 KB)
    __shared__ short Vt[kHeads][32 * 64];   // V^T[d][m] bf16, swizzled (16 KB)
    __shared__ float rpl[kHeads][169];      // rpb slice per head (2.7 KB)
    const int tid = threadIdx.x, wave = tid >> 6, lane = tid & 63;
    const int quad = lane >> 4, l16 = lane & 15;
    const int head = wave;
    const size_t wbase = (size_t)blockIdx.x * kWinElems;

    // ---- stage rpb for this wave's own head (intra-wave producer/consumer) --
    for (int i = lane; i < 169; i += 64) rpl[head][i] = rpb[i * kHeads + head];

    // ---- Q/K fragments straight from global (issue early, long latency) ----
    bf16x8 qf[4], kf[4];
    const bf16* qp = qbuf + wbase + head * kHD + quad * 8;
    const bf16* kp = kbuf + wbase + head * kHD + quad * 8;
    #pragma unroll
    for (int t = 0; t < 4; t++) {
        qf[t] = *(const bf16x8*)(qp + (size_t)(t * 16 + l16) * kC);
        kf[t] = *(const bf16x8*)(kp + (size_t)(t * 16 + l16) * kC);
    }

    // ---- V^T staging: [d][m] bf16, cols m>=49 zeroed, XOR-swizzled ----
    #pragma unroll
    for (int h = 0; h < 4; h++) {
        for (int i = tid; i < 1024; i += 256) {       // 64 m-slots x 16 d-pairs
            const int m = i >> 4, d2 = (i & 15) << 1;
            int val = 0;
            if (m < 49) val = *(const int*)(vbuf + wbase + (size_t)m * kC + h * kHD + d2);
            Vt[h][d2 * 64 + (m ^ ((d2 & 7) << 3))]         = (short)(val & 0xffff);
            Vt[h][(d2 + 1) * 64 + (m ^ (((d2 + 1) & 7) << 3))] = (short)(val >> 16);
        }
    }

    // ---- S = Q K^T : 16 MFMAs; D elem = S[n=nt*16+quad*4+i][m=mt*16+l16] ----
    f32x4 S[4][4];
    #pragma unroll
    for (int nt = 0; nt < 4; nt++)
        #pragma unroll
        for (int mt = 0; mt < 4; mt++)
            S[nt][mt] = __builtin_amdgcn_mfma_f32_16x16x32_bf16(
                qf[nt], kf[mt], (f32x4){0.f, 0.f, 0.f, 0.f}, 0, 0, 0);

    __syncthreads();   // Vt (cross-wave) ready; Pl/rpl are intra-wave only

    // ---- bias index precompute: idx = 13*(rn-rm+6) + (cn-cm+6) ----
    int an[4][4];
    #pragma unroll
    for (int nt = 0; nt < 4; nt++)
        #pragma unroll
        for (int i = 0; i < 4; i++) {
            const int n = nt * 16 + quad * 4 + i;
            an[nt][i] = 13 * (n / 7) + (n % 7) + 84;
        }
    int bm[4]; bool mok[4];
    #pragma unroll
    for (int mt = 0; mt < 4; mt++) {
        const int m = mt * 16 + l16;
        bm[mt] = 13 * (m / 7) + (m % 7);
        mok[mt] = (m < 49);
    }

    // ---- wave-parallel softmax, row (nt,i) at a time; write P bf16 to LDS --
    const float* rp = rpl[head];
    #pragma unroll
    for (int nt = 0; nt < 4; nt++)
        #pragma unroll
        for (int i = 0; i < 4; i++) {
            float sv[4];
            #pragma unroll
            for (int mt = 0; mt < 4; mt++) {
                int idx = an[nt][i] - bm[mt];
                idx = ((unsigned)idx > 168u) ? 0 : idx;
                sv[mt] = mok[mt] ? (S[nt][mt][i] * kScale + rp[idx]) : -1e30f;
            }
            float mx = fmaxf(fmaxf(sv[0], sv[1]), fmaxf(sv[2], sv[3]));
            #pragma unroll
            for (int off = 1; off < 16; off <<= 1) mx = fmaxf(mx, __shfl_xor(mx, off));
            float e[4];
            float sum = 0.f;
            #pragma unroll
            for (int mt = 0; mt < 4; mt++) { e[mt] = __expf(sv[mt] - mx); sum += e[mt]; }
            #pragma unroll
            for (int off = 1; off < 16; off <<= 1) sum += __shfl_xor(sum, off);
            const float inv = 1.f / sum;
            const int prow = nt * 16 + quad * 4 + i;
            short* pr = &Pl[head][prow * 64];
            const int sw = (prow & 7) << 3;
            #pragma unroll
            for (int mt = 0; mt < 4; mt++)
                pr[(mt * 16 + l16) ^ sw] = f2bs(e[mt] * inv);
        }

    // ---- PV: O^T tiles via MFMA. A = V^T (rows d), B = P (rows n) ----
    bf16x8 va[2][2], pb2[4][2];
    #pragma unroll
    for (int dt = 0; dt < 2; dt++)
        #pragma unroll
        for (int ks = 0; ks < 2; ks++) {
            const int r = dt * 16 + l16;
            va[dt][ks] = *(const bf16x8*)&Vt[head][r * 64 + ((ks * 32 + quad * 8) ^ ((r & 7) << 3))];
        }
    #pragma unroll
    for (int nt = 0; nt < 4; nt++)
        #pragma unroll
        for (int ks = 0; ks < 2; ks++) {
            const int r = nt * 16 + l16;
            pb2[nt][ks] = *(const bf16x8*)&Pl[head][r * 64 + ((ks * 32 + quad * 8) ^ ((r & 7) << 3))];
        }
    f32x4 o[2][4];
    #pragma unroll
    for (int dt = 0; dt < 2; dt++)
        #pragma unroll
        for (int nt = 0; nt < 4; nt++) {
            f32x4 a = __builtin_amdgcn_mfma_f32_16x16x32_bf16(
                va[dt][0], pb2[nt][0], (f32x4){0.f, 0.f, 0.f, 0.f}, 0, 0, 0);
            o[dt][nt] = __builtin_amdgcn_mfma_f32_16x16x32_bf16(
                va[dt][1], pb2[nt][1], a, 0, 0, 0);
        }

    // ---- writeback: D row = d (quad*4+i contiguous) -> 8B stores ----
    #pragma unroll
    for (int nt = 0; nt < 4; nt++) {
        const int n = nt * 16 + l16;
        if (n < 49) {
            bf16* dst = qbuf + wbase + (size_t)n * kC + head * kHD + quad * 4;
            #pragma unroll
            for (int dt = 0; dt < 2; dt++) {
                short4v p;
                #pragma unroll
                for (int i = 0; i < 4; i++) p[i] = f2bs(o[dt][nt][i]);
                *(short4v*)(dst + dt * 16) = p;
            }
        }
    }
}

// ---------------------------------------------------------------------------
// K3 (MFMA): window-reverse gather + output projection + residual -> d_out.
__global__ __launch_bounds__(256) void k_proj_mfma(
    const bf16* __restrict__ ao, const short* __restrict__ pwb,
    const float* __restrict__ pb, const float* __restrict__ x,
    float* __restrict__ out)
{
    __shared__ short As[32 * kAP];
    const int tid = threadIdx.x, wave = tid >> 6, lane = tid & 63;
    const int quad = lane >> 4, l16 = lane & 15;
    const int row0 = blockIdx.x * 32;
    const int c0 = lane * 2;

    for (int n = wave; n < 32; n += 4) {
        const int gr = row0 + n;
        const int b = gr / kL, l = gr - b * kL;
        const int h = l / kW, w_ = l - h * kW;
        const size_t off = (size_t)(((b << 8) + (h / 7) * 16 + (w_ / 7))) * kWinElems
                         + ((h % 7) * 7 + (w_ % 7)) * kC;
        *(int*)&As[n * kAP + c0] = *(const int*)((const short*)ao + off + c0);
    }
    __syncthreads();

    bf16x8 bfrag[2][4];
    #pragma unroll
    for (int mt = 0; mt < 2; mt++)
        #pragma unroll
        for (int ks = 0; ks < 4; ks++)
            bfrag[mt][ks] = *(const bf16x8*)&As[(mt * 16 + l16) * kAP + ks * 32 + quad * 8];

    #pragma unroll
    for (int j = 0; j < 2; j++) {
        const int nt = wave * 2 + j;
        const int cb = nt * 16 + quad * 4;
        f32x4 a0 = { pb[cb], pb[cb + 1], pb[cb + 2], pb[cb + 3] };
        f32x4 a1 = a0;
        #pragma unroll
        for (int ks = 0; ks < 4; ks++) {
            const bf16x8 af = *(const bf16x8*)(pwb + (size_t)(nt * 16 + l16) * kC + ks * 32 + quad * 8);
            a0 = __builtin_amdgcn_mfma_f32_16x16x32_bf16(af, bfrag[0][ks], a0, 0, 0, 0);
            a1 = __builtin_amdgcn_mfma_f32_16x16x32_bf16(af, bfrag[1][ks], a1, 0, 0, 0);
        }
        #pragma unroll
        for (int mt = 0; mt < 2; mt++) {
            const size_t gr = row0 + mt * 16 + l16;
            float4 res = *(const float4*)(x + gr * kC + cb);
            const f32x4 a = mt ? a1 : a0;
            res.x += a[0]; res.y += a[1]; res.z += a[2]; res.w += a[3];
            *(float4*)(out + gr * kC + cb) = res;
        }
    }
}

// ---------------------------------------------------------------------------
// K4 (MFMA): LN2 + fc1 + exact GELU + fc2 + residual, in-place on d_out.
constexpr int kMT = 32;

__global__ __launch_bounds__(256, 4) void k_mlp_mfma(
    float* __restrict__ out,
    const float* __restrict__ g2, const float* __restrict__ b2v,
    const short* __restrict__ w1b, const float* __restrict__ bb1,
    const short* __restrict__ w2b, const float* __restrict__ bb2)
{
    __shared__ short LDSu[kMT * kHP];            // 33280 B (A_s/H_s union)
    short* const A_s = LDSu;
    short* const H_s = LDSu;
    const int tid = threadIdx.x, wave = tid >> 6, lane = tid & 63;
    const int quad = lane >> 4, l16 = lane & 15;
    const size_t row0 = (size_t)blockIdx.x * kMT;
    const int c0 = lane * 2;

    const float gg0 = g2[c0], gg1 = g2[c0 + 1];
    const float bv0 = b2v[c0], bv1 = b2v[c0 + 1];
    float2 xv[8];
    #pragma unroll
    for (int it = 0; it < 8; it++)
        xv[it] = *(const float2*)(out + (row0 + wave + it * 4) * kC + c0);
    float s[8], q[8];
    #pragma unroll
    for (int it = 0; it < 8; it++) {
        s[it] = xv[it].x + xv[it].y;
        q[it] = xv[it].x * xv[it].x + xv[it].y * xv[it].y;
    }
    #pragma unroll
    for (int off = 32; off > 0; off >>= 1) {
        #pragma unroll
        for (int it = 0; it < 8; it++) {
            s[it] += __shfl_xor(s[it], off);
            q[it] += __shfl_xor(q[it], off);
        }
    }
    #pragma unroll
    for (int it = 0; it < 8; it++) {
        const int n = wave + it * 4;
        const float mu = s[it] * (1.f / kC);
        const float iv = rsqrtf(q[it] * (1.f / kC) - mu * mu + kEps);
        const short h0 = f2bs((xv[it].x - mu) * iv * gg0 + bv0);
        const short h1 = f2bs((xv[it].y - mu) * iv * gg1 + bv1);
        *(int*)&A_s[n * kAP + c0] =
            ((int)(unsigned short)h1 << 16) | (int)(unsigned short)h0;
    }
    __syncthreads();

    bf16x8 bfrag[2][4];
    #pragma unroll
    for (int mt = 0; mt < 2; mt++)
        #pragma unroll
        for (int ks = 0; ks < 4; ks++)
            bfrag[mt][ks] = *(const bf16x8*)&A_s[(mt * 16 + l16) * kAP + ks * 32 + quad * 8];
    __syncthreads();

    const short* wbase = w1b + (size_t)(wave * 128 + l16) * kC + quad * 8;
    auto loadw1 = [&](bf16x8* dst, int t) {
        #pragma unroll
        for (int ks = 0; ks < 4; ks++)
            dst[ks] = *(const bf16x8*)(wbase + (size_t)t * (16 * kC) + ks * 32);
    };
    auto mfma8 = [&](f32x4* a, const bf16x8* w) {
        #pragma unroll
        for (int ks = 0; ks < 4; ks++) {
            a[0] = __builtin_amdgcn_mfma_f32_16x16x32_bf16(w[ks], bfrag[0][ks], a[0], 0, 0, 0);
            a[1] = __builtin_amdgcn_mfma_f32_16x16x32_bf16(w[ks], bfrag[1][ks], a[1], 0, 0, 0);
        }
    };
    #pragma unroll
    for (int g = 0; g < 2; g++) {
        f32x4 acc[4][2];
        #pragma unroll
        for (int t = 0; t < 4; t++) {
            const float4 bi = *(const float4*)(bb1 + (wave * 8 + g * 4 + t) * 16 + quad * 4);
            acc[t][0] = (f32x4){ bi.x, bi.y, bi.z, bi.w };
            acc[t][1] = acc[t][0];
        }
        bf16x8 wA[4], wB[4];
        loadw1(wA, g * 4 + 0);
        loadw1(wB, g * 4 + 1);
        mfma8(acc[0], wA);
        loadw1(wA, g * 4 + 2);
        mfma8(acc[1], wB);
        loadw1(wB, g * 4 + 3);
        mfma8(acc[2], wA);
        mfma8(acc[3], wB);
        #pragma unroll
        for (int t = 0; t < 4; t++) {
            const int nb = (wave * 8 + g * 4 + t) * 16 + quad * 4;
            #pragma unroll
            for (int mt = 0; mt < 2; mt++) {
                short4v p;
                #pragma unroll
                for (int i = 0; i < 4; i++) {
                    const float a = acc[t][mt][i];
                    p[i] = f2bs(0.5f * a * (1.f + erff(a * 0.70710678118f)));
                }
                *(short4v*)&H_s[(mt * 16 + l16) * kHP + nb] = p;
            }
        }
    }
    __syncthreads();

    const int ct0 = wave * 2;
    f32x4 acc2[2][2];
    #pragma unroll
    for (int t = 0; t < 2; t++) {
        const float4 bi = *(const float4*)(bb2 + (ct0 + t) * 16 + quad * 4);
        acc2[t][0] = (f32x4){ bi.x, bi.y, bi.z, bi.w };
        acc2[t][1] = acc2[t][0];
    }
    const short* w2base = w2b + (size_t)(ct0 * 16 + l16) * kMLP + quad * 8;
    const short* hbase0 = &H_s[l16 * kHP + quad * 8];
    const short* hbase1 = &H_s[(16 + l16) * kHP + quad * 8];
    auto loadh = [&](bf16x8* h, bf16x8* w, int kk) {
        h[0] = *(const bf16x8*)(hbase0 + kk * 32);
        h[1] = *(const bf16x8*)(hbase1 + kk * 32);
        w[0] = *(const bf16x8*)(w2base + kk * 32);
        w[1] = *(const bf16x8*)(w2base + (size_t)16 * kMLP + kk * 32);
    };
    auto mfma4 = [&](const bf16x8* h, const bf16x8* w) {
        acc2[0][0] = __builtin_amdgcn_mfma_f32_16x16x32_bf16(w[0], h[0], acc2[0][0], 0, 0, 0);
        acc2[0][1] = __builtin_amdgcn_mfma_f32_16x16x32_bf16(w[0], h[1], acc2[0][1], 0, 0, 0);
        acc2[1][0] = __builtin_amdgcn_mfma_f32_16x16x32_bf16(w[1], h[0], acc2[1][0], 0, 0, 0);
        acc2[1][1] = __builtin_amdgcn_mfma_f32_16x16x32_bf16(w[1], h[1], acc2[1][1], 0, 0, 0);
    };
    bf16x8 hA[2], wwA[2], hB[2], wwB[2];
    loadh(hA, wwA, 0);
    #pragma unroll
    for (int kk = 0; kk < 16; kk += 2) {
        loadh(hB, wwB, kk + 1);
        mfma4(hA, wwA);
        if (kk + 2 < 16) loadh(hA, wwA, kk + 2);
        mfma4(hB, wwB);
    }

    #pragma unroll
    for (int t = 0; t < 2; t++) {
        const int cbv = (ct0 + t) * 16 + quad * 4;
        #pragma unroll
        for (int mt = 0; mt < 2; mt++) {
            const size_t m = row0 + mt * 16 + l16;
            float4 res = *(const float4*)(out + m * kC + cbv);
            res.x += acc2[t][mt][0]; res.y += acc2[t][mt][1];
            res.z += acc2[t][mt][2]; res.w += acc2[t][mt][3];
            *(float4*)(out + m * kC + cbv) = res;
        }
    }
}

// ---------------------------------------------------------------------------
extern "C" void kernel_launch(void* const* d_in, const int* in_sizes, int n_in,
                              void* d_out, int out_size, void* d_ws, size_t ws_size,
                              hipStream_t stream) {
    (void)in_sizes; (void)n_in; (void)out_size; (void)ws_size;
    const float* x      = (const float*)d_in[0];
    const float* v      = (const float*)d_in[1];
    const float* n1g    = (const float*)d_in[2];
    const float* n1b    = (const float*)d_in[3];
    const float* nvg    = (const float*)d_in[4];
    const float* nvb    = (const float*)d_in[5];
    const float* q_w    = (const float*)d_in[6];
    const float* q_b    = (const float*)d_in[7];
    const float* kv_w   = (const float*)d_in[8];
    const float* kv_b   = (const float*)d_in[9];
    const float* rpb    = (const float*)d_in[10];
    const float* proj_w = (const float*)d_in[11];
    const float* proj_b = (const float*)d_in[12];
    const float* n2g    = (const float*)d_in[13];
    const float* n2b    = (const float*)d_in[14];
    const float* fc1_w  = (const float*)d_in[15];
    const float* fc1_b  = (const float*)d_in[16];
    const float* fc2_w  = (const float*)d_in[17];
    const float* fc2_b  = (const float*)d_in[18];

    const size_t winTot = (size_t)4096 * kWinElems;   // 25,690,112 elems
    bf16* qbuf = (bf16*)d_ws;
    bf16* kbuf = qbuf + winTot;
    bf16* vbuf = kbuf + winTot;                        // 154 MB
    short* wcvt = (short*)(vbuf + winTot);             // bf16 weight arena
    short* qwb  = wcvt;                                // 16384
    short* kvwb = qwb + 16384;                         // 32768
    short* pwb  = kvwb + 32768;                        // 16384
    short* w1b  = pwb + 16384;                         // 65536
    short* w2b  = w1b + 65536;                         // 65536
    float* outb = (float*)d_out;

    k_cvt<<<768, 256, 0, stream>>>(q_w, kv_w, proj_w, fc1_w, fc2_w, wcvt);
    k_ln_qkv_mfma<<<6272, 256, 0, stream>>>(x, v, n1g, n1b, nvg, nvb,
                                            qwb, q_b, kvwb, kv_b, qbuf, kbuf, vbuf);
    k_attn_mfma<<<4096, 256, 0, stream>>>(qbuf, kbuf, vbuf, rpb);
    k_proj_mfma<<<6272, 256, 0, stream>>>(qbuf, pwb, proj_b, x, outb);
    k_mlp_mfma<<<6272, 256, 0, stream>>>(outb, n2g, n2b, w1b, fc1_b, w2b, fc2_b);
}

// Round 3
// 726.397 us; speedup vs baseline: 1.4934x; 1.0281x over previous
//
#include <hip/hip_runtime.h>
#include <hip/hip_bf16.h>
#include <math.h>

typedef __hip_bfloat16 bf16;
typedef __hip_bfloat162 bf162;
typedef __attribute__((ext_vector_type(8))) short bf16x8;   // MFMA A/B frag (4 VGPRs)
typedef __attribute__((ext_vector_type(4))) short short4v;  // 8B store
typedef __attribute__((ext_vector_type(4))) float f32x4;    // MFMA C/D frag

__device__ __forceinline__ float b2f(bf16 x){ return __bfloat162float(x); }
__device__ __forceinline__ bf16  f2b(float x){ return __float2bfloat16(x); }
__device__ __forceinline__ short f2bs(float x){ bf16 h = __float2bfloat16(x); return *(short*)&h; }

constexpr int kH = 112, kW = 112, kC = 128, kHeads = 4, kWS = 7;
constexpr int kN = 49, kHD = 32, kL = kH * kW;      // L = 12544
constexpr int kWinElems = kN * kC;                  // 6272
constexpr int kMLP = 512;
constexpr float kEps = 1e-5f;
constexpr float kScale = 0.17677669529663687f;      // 1/sqrt(32)
constexpr int kAP = 136;      // LDS row stride (bf16): 272B = 17*16
constexpr int kHP = 520;      // MLP hidden stride
constexpr int kXP = 132;      // Xo f32 row stride (528B, 16B-aligned)

// ---------------------------------------------------------------------------
// K0: convert all weight matrices fp32 -> bf16 into one ws arena.
__global__ __launch_bounds__(256) void k_cvt(
    const float* __restrict__ qw, const float* __restrict__ kvw,
    const float* __restrict__ pw, const float* __restrict__ w1,
    const float* __restrict__ w2, short* __restrict__ dst)
{
    const int i = blockIdx.x * 256 + threadIdx.x;   // 196608 total
    float val;
    if (i < 16384)       val = qw[i];
    else if (i < 49152)  val = kvw[i - 16384];
    else if (i < 65536)  val = pw[i - 49152];
    else if (i < 131072) val = w1[i - 65536];
    else                 val = w2[i - 131072];
    dst[i] = f2bs(val);
}

// ---------------------------------------------------------------------------
// K1 (MFMA): LN(x), LN(v) + Q/K/V projection + window-partition scatter.
__global__ __launch_bounds__(256) void k_ln_qkv_mfma(
    const float* __restrict__ x, const float* __restrict__ v,
    const float* __restrict__ n1g, const float* __restrict__ n1b,
    const float* __restrict__ nvg, const float* __restrict__ nvb,
    const short* __restrict__ qwb, const float* __restrict__ qb,
    const short* __restrict__ kvwb, const float* __restrict__ kvb,
    bf16* __restrict__ qo, bf16* __restrict__ ko, bf16* __restrict__ vo)
{
    __shared__ short Xs[32 * kAP], Vs[32 * kAP];
    const int tid = threadIdx.x, wave = tid >> 6, lane = tid & 63;
    const int quad = lane >> 4, l16 = lane & 15;
    const int row0 = blockIdx.x * 32;
    const int c0 = lane * 2;

    for (int n = wave; n < 32; n += 4) {
        const size_t r = (size_t)(row0 + n) * kC;
        const float2 xv = *(const float2*)(x + r + c0);
        const float2 vv = *(const float2*)(v + r + c0);
        float sx = xv.x + xv.y, qx = xv.x * xv.x + xv.y * xv.y;
        float sv = vv.x + vv.y, qv = vv.x * vv.x + vv.y * vv.y;
        #pragma unroll
        for (int off = 32; off > 0; off >>= 1) {
            sx += __shfl_xor(sx, off); qx += __shfl_xor(qx, off);
            sv += __shfl_xor(sv, off); qv += __shfl_xor(qv, off);
        }
        const float mux = sx * (1.f / kC);
        const float ivx = rsqrtf(qx * (1.f / kC) - mux * mux + kEps);
        const float muv = sv * (1.f / kC);
        const float ivv = rsqrtf(qv * (1.f / kC) - muv * muv + kEps);
        Xs[n * kAP + c0]     = f2bs((xv.x - mux) * ivx * n1g[c0] + n1b[c0]);
        Xs[n * kAP + c0 + 1] = f2bs((xv.y - mux) * ivx * n1g[c0 + 1] + n1b[c0 + 1]);
        Vs[n * kAP + c0]     = f2bs((vv.x - muv) * ivv * nvg[c0] + nvb[c0]);
        Vs[n * kAP + c0 + 1] = f2bs((vv.y - muv) * ivv * nvg[c0 + 1] + nvb[c0 + 1]);
    }
    __syncthreads();

    int woff[2];
    #pragma unroll
    for (int mt = 0; mt < 2; mt++) {
        const int gr = row0 + mt * 16 + l16;
        const int b = gr / kL, l = gr - b * kL;
        const int h = l / kW, w_ = l - h * kW;
        woff[mt] = ((b << 8) + (h / 7) * 16 + (w_ / 7)) * kWinElems
                 + ((h % 7) * 7 + (w_ % 7)) * kC;
    }

    bf16x8 xf[2][4], vf[2][4];
    #pragma unroll
    for (int mt = 0; mt < 2; mt++)
        #pragma unroll
        for (int ks = 0; ks < 4; ks++) {
            xf[mt][ks] = *(const bf16x8*)&Xs[(mt * 16 + l16) * kAP + ks * 32 + quad * 8];
            vf[mt][ks] = *(const bf16x8*)&Vs[(mt * 16 + l16) * kAP + ks * 32 + quad * 8];
        }

    #pragma unroll
    for (int j = 0; j < 6; j++) {
        const int nt = wave * 6 + j;
        const bool isq = (nt < 8);
        const short* wmat = isq ? qwb : kvwb;
        const int wr0 = (isq ? nt : nt - 8) * 16;
        const float* bias = isq ? qb : kvb;
        const int bidx = wr0 + quad * 4;
        f32x4 a0 = { bias[bidx], bias[bidx + 1], bias[bidx + 2], bias[bidx + 3] };
        f32x4 a1 = a0;
        if (isq) {
            #pragma unroll
            for (int ks = 0; ks < 4; ks++) {
                const bf16x8 af = *(const bf16x8*)(wmat + (size_t)(wr0 + l16) * kC + ks * 32 + quad * 8);
                a0 = __builtin_amdgcn_mfma_f32_16x16x32_bf16(af, xf[0][ks], a0, 0, 0, 0);
                a1 = __builtin_amdgcn_mfma_f32_16x16x32_bf16(af, xf[1][ks], a1, 0, 0, 0);
            }
        } else {
            #pragma unroll
            for (int ks = 0; ks < 4; ks++) {
                const bf16x8 af = *(const bf16x8*)(wmat + (size_t)(wr0 + l16) * kC + ks * 32 + quad * 8);
                a0 = __builtin_amdgcn_mfma_f32_16x16x32_bf16(af, vf[0][ks], a0, 0, 0, 0);
                a1 = __builtin_amdgcn_mfma_f32_16x16x32_bf16(af, vf[1][ks], a1, 0, 0, 0);
            }
        }
        bf16* dst = isq ? qo : (nt < 16 ? ko : vo);
        const int cb = (isq ? nt : (nt < 16 ? nt - 8 : nt - 16)) * 16 + quad * 4;
        short4v p0, p1;
        #pragma unroll
        for (int i = 0; i < 4; i++) { p0[i] = f2bs(a0[i]); p1[i] = f2bs(a1[i]); }
        *(short4v*)((short*)dst + (size_t)woff[0] + cb) = p0;
        *(short4v*)((short*)dst + (size_t)woff[1] + cb) = p1;
    }
}

// ---------------------------------------------------------------------------
// K2 (MFMA): attention per window; wave = head.
__global__ __launch_bounds__(256, 3) void k_attn_mfma(
    bf16* __restrict__ qbuf, const bf16* __restrict__ kbuf,
    const bf16* __restrict__ vbuf, const float* __restrict__ rpb)
{
    __shared__ short Pl[kHeads][64 * 64];   // P[n][m] bf16, swizzled (32 KB)
    __shared__ short Vt[kHeads][32 * 64];   // V^T[d][m] bf16, swizzled (16 KB)
    __shared__ float rpl[kHeads][169];      // rpb slice per head (2.7 KB)
    const int tid = threadIdx.x, wave = tid >> 6, lane = tid & 63;
    const int quad = lane >> 4, l16 = lane & 15;
    const int head = wave;
    const size_t wbase = (size_t)blockIdx.x * kWinElems;

    for (int i = lane; i < 169; i += 64) rpl[head][i] = rpb[i * kHeads + head];

    bf16x8 qf[4], kf[4];
    const bf16* qp = qbuf + wbase + head * kHD + quad * 8;
    const bf16* kp = kbuf + wbase + head * kHD + quad * 8;
    #pragma unroll
    for (int t = 0; t < 4; t++) {
        qf[t] = *(const bf16x8*)(qp + (size_t)(t * 16 + l16) * kC);
        kf[t] = *(const bf16x8*)(kp + (size_t)(t * 16 + l16) * kC);
    }

    #pragma unroll
    for (int h = 0; h < 4; h++) {
        for (int i = tid; i < 1024; i += 256) {       // 64 m-slots x 16 d-pairs
            const int m = i >> 4, d2 = (i & 15) << 1;
            int val = 0;
            if (m < 49) val = *(const int*)(vbuf + wbase + (size_t)m * kC + h * kHD + d2);
            Vt[h][d2 * 64 + (m ^ ((d2 & 7) << 3))]         = (short)(val & 0xffff);
            Vt[h][(d2 + 1) * 64 + (m ^ (((d2 + 1) & 7) << 3))] = (short)(val >> 16);
        }
    }

    f32x4 S[4][4];
    #pragma unroll
    for (int nt = 0; nt < 4; nt++)
        #pragma unroll
        for (int mt = 0; mt < 4; mt++)
            S[nt][mt] = __builtin_amdgcn_mfma_f32_16x16x32_bf16(
                qf[nt], kf[mt], (f32x4){0.f, 0.f, 0.f, 0.f}, 0, 0, 0);

    __syncthreads();   // Vt (cross-wave) ready

    int an[4][4];
    #pragma unroll
    for (int nt = 0; nt < 4; nt++)
        #pragma unroll
        for (int i = 0; i < 4; i++) {
            const int n = nt * 16 + quad * 4 + i;
            an[nt][i] = 13 * (n / 7) + (n % 7) + 84;
        }
    int bm[4]; bool mok[4];
    #pragma unroll
    for (int mt = 0; mt < 4; mt++) {
        const int m = mt * 16 + l16;
        bm[mt] = 13 * (m / 7) + (m % 7);
        mok[mt] = (m < 49);
    }

    const float* rp = rpl[head];
    #pragma unroll
    for (int nt = 0; nt < 4; nt++)
        #pragma unroll
        for (int i = 0; i < 4; i++) {
            float sv[4];
            #pragma unroll
            for (int mt = 0; mt < 4; mt++) {
                int idx = an[nt][i] - bm[mt];
                idx = ((unsigned)idx > 168u) ? 0 : idx;
                sv[mt] = mok[mt] ? (S[nt][mt][i] * kScale + rp[idx]) : -1e30f;
            }
            float mx = fmaxf(fmaxf(sv[0], sv[1]), fmaxf(sv[2], sv[3]));
            #pragma unroll
            for (int off = 1; off < 16; off <<= 1) mx = fmaxf(mx, __shfl_xor(mx, off));
            float e[4];
            float sum = 0.f;
            #pragma unroll
            for (int mt = 0; mt < 4; mt++) { e[mt] = __expf(sv[mt] - mx); sum += e[mt]; }
            #pragma unroll
            for (int off = 1; off < 16; off <<= 1) sum += __shfl_xor(sum, off);
            const float inv = 1.f / sum;
            const int prow = nt * 16 + quad * 4 + i;
            short* pr = &Pl[head][prow * 64];
            const int sw = (prow & 7) << 3;
            #pragma unroll
            for (int mt = 0; mt < 4; mt++)
                pr[(mt * 16 + l16) ^ sw] = f2bs(e[mt] * inv);
        }

    bf16x8 va[2][2], pb2[4][2];
    #pragma unroll
    for (int dt = 0; dt < 2; dt++)
        #pragma unroll
        for (int ks = 0; ks < 2; ks++) {
            const int r = dt * 16 + l16;
            va[dt][ks] = *(const bf16x8*)&Vt[head][r * 64 + ((ks * 32 + quad * 8) ^ ((r & 7) << 3))];
        }
    #pragma unroll
    for (int nt = 0; nt < 4; nt++)
        #pragma unroll
        for (int ks = 0; ks < 2; ks++) {
            const int r = nt * 16 + l16;
            pb2[nt][ks] = *(const bf16x8*)&Pl[head][r * 64 + ((ks * 32 + quad * 8) ^ ((r & 7) << 3))];
        }
    f32x4 o[2][4];
    #pragma unroll
    for (int dt = 0; dt < 2; dt++)
        #pragma unroll
        for (int nt = 0; nt < 4; nt++) {
            f32x4 a = __builtin_amdgcn_mfma_f32_16x16x32_bf16(
                va[dt][0], pb2[nt][0], (f32x4){0.f, 0.f, 0.f, 0.f}, 0, 0, 0);
            o[dt][nt] = __builtin_amdgcn_mfma_f32_16x16x32_bf16(
                va[dt][1], pb2[nt][1], a, 0, 0, 0);
        }

    #pragma unroll
    for (int nt = 0; nt < 4; nt++) {
        const int n = nt * 16 + l16;
        if (n < 49) {
            bf16* dst = qbuf + wbase + (size_t)n * kC + head * kHD + quad * 4;
            #pragma unroll
            for (int dt = 0; dt < 2; dt++) {
                short4v p;
                #pragma unroll
                for (int i = 0; i < 4; i++) p[i] = f2bs(o[dt][nt][i]);
                *(short4v*)(dst + dt * 16) = p;
            }
        }
    }
}

// ---------------------------------------------------------------------------
// K3+K4 fused: window-reverse gather + proj + residual (xo in LDS f32) +
// LN2 + fc1 + exact GELU + fc2 + single final write (xo + mlp).
// LDS: Xo f32 32x132 (16896B) + union{As gather, A_s bf16, H_s} (33280B)
// = 50176B -> 3 blocks/CU.
constexpr int kMT = 32;

__global__ __launch_bounds__(256, 3) void k_proj_mlp(
    const bf16* __restrict__ ao, const short* __restrict__ pwb,
    const float* __restrict__ pb, const float* __restrict__ x,
    float* __restrict__ out,
    const float* __restrict__ g2, const float* __restrict__ b2v,
    const short* __restrict__ w1b, const float* __restrict__ bb1,
    const short* __restrict__ w2b, const float* __restrict__ bb2)
{
    __shared__ float Xo[kMT * kXP];              // xo tile, f32 (lives to end)
    __shared__ short U[kMT * kHP];               // union: As / A_s / H_s
    short* const As  = U;
    short* const A_s = U;
    short* const H_s = U;
    const int tid = threadIdx.x, wave = tid >> 6, lane = tid & 63;
    const int quad = lane >> 4, l16 = lane & 15;
    const size_t row0 = (size_t)blockIdx.x * kMT;
    const int c0 = lane * 2;

    // ================= Phase A: gather + proj + residual -> Xo =============
    for (int n = wave; n < 32; n += 4) {
        const int gr = (int)row0 + n;
        const int b = gr / kL, l = gr - b * kL;
        const int h = l / kW, w_ = l - h * kW;
        const size_t off = (size_t)(((b << 8) + (h / 7) * 16 + (w_ / 7))) * kWinElems
                         + ((h % 7) * 7 + (w_ % 7)) * kC;
        *(int*)&As[n * kAP + c0] = *(const int*)((const short*)ao + off + c0);
    }
    __syncthreads();                             // sync1: As ready

    bf16x8 bfrag[2][4];
    #pragma unroll
    for (int mt = 0; mt < 2; mt++)
        #pragma unroll
        for (int ks = 0; ks < 4; ks++)
            bfrag[mt][ks] = *(const bf16x8*)&As[(mt * 16 + l16) * kAP + ks * 32 + quad * 8];

    // residual loads issued early (long-latency, hidden under proj MFMAs)
    float4 res[2][2];
    #pragma unroll
    for (int j = 0; j < 2; j++)
        #pragma unroll
        for (int mt = 0; mt < 2; mt++)
            res[j][mt] = *(const float4*)(x + (row0 + mt * 16 + l16) * kC
                                            + (wave * 2 + j) * 16 + quad * 4);

    #pragma unroll
    for (int j = 0; j < 2; j++) {
        const int nt = wave * 2 + j;
        const int cb = nt * 16 + quad * 4;
        f32x4 a0 = { pb[cb], pb[cb + 1], pb[cb + 2], pb[cb + 3] };
        f32x4 a1 = a0;
        #pragma unroll
        for (int ks = 0; ks < 4; ks++) {
            const bf16x8 af = *(const bf16x8*)(pwb + (size_t)(nt * 16 + l16) * kC + ks * 32 + quad * 8);
            a0 = __builtin_amdgcn_mfma_f32_16x16x32_bf16(af, bfrag[0][ks], a0, 0, 0, 0);
            a1 = __builtin_amdgcn_mfma_f32_16x16x32_bf16(af, bfrag[1][ks], a1, 0, 0, 0);
        }
        #pragma unroll
        for (int mt = 0; mt < 2; mt++) {
            const f32x4 a = mt ? a1 : a0;
            float4 r = res[j][mt];
            r.x += a[0]; r.y += a[1]; r.z += a[2]; r.w += a[3];
            *(float4*)&Xo[(mt * 16 + l16) * kXP + cb] = r;
        }
    }
    __syncthreads();    // sync2: Xo complete; As reads done -> U reusable

    // ================= Phase B: LN2 from Xo -> A_s (bf16) ==================
    const float gg0 = g2[c0], gg1 = g2[c0 + 1];
    const float bv0 = b2v[c0], bv1 = b2v[c0 + 1];
    float2 xv[8];
    #pragma unroll
    for (int it = 0; it < 8; it++)
        xv[it] = *(const float2*)&Xo[(wave + it * 4) * kXP + c0];
    float s[8], q[8];
    #pragma unroll
    for (int it = 0; it < 8; it++) {
        s[it] = xv[it].x + xv[it].y;
        q[it] = xv[it].x * xv[it].x + xv[it].y * xv[it].y;
    }
    #pragma unroll
    for (int off = 32; off > 0; off >>= 1) {
        #pragma unroll
        for (int it = 0; it < 8; it++) {
            s[it] += __shfl_xor(s[it], off);
            q[it] += __shfl_xor(q[it], off);
        }
    }
    #pragma unroll
    for (int it = 0; it < 8; it++) {
        const int n = wave + it * 4;
        const float mu = s[it] * (1.f / kC);
        const float iv = rsqrtf(q[it] * (1.f / kC) - mu * mu + kEps);
        const short h0 = f2bs((xv[it].x - mu) * iv * gg0 + bv0);
        const short h1 = f2bs((xv[it].y - mu) * iv * gg1 + bv1);
        *(int*)&A_s[n * kAP + c0] =
            ((int)(unsigned short)h1 << 16) | (int)(unsigned short)h0;
    }
    __syncthreads();    // sync3: A_s ready

    bf16x8 bfrag2[2][4];
    #pragma unroll
    for (int mt = 0; mt < 2; mt++)
        #pragma unroll
        for (int ks = 0; ks < 4; ks++)
            bfrag2[mt][ks] = *(const bf16x8*)&A_s[(mt * 16 + l16) * kAP + ks * 32 + quad * 8];
    __syncthreads();    // sync4: A_s reads done -> U reusable for H_s

    // ================= Phase C: fc1 + GELU -> H_s ==========================
    const short* wbase = w1b + (size_t)(wave * 128 + l16) * kC + quad * 8;
    auto loadw1 = [&](bf16x8* dst, int t) {
        #pragma unroll
        for (int ks = 0; ks < 4; ks++)
            dst[ks] = *(const bf16x8*)(wbase + (size_t)t * (16 * kC) + ks * 32);
    };
    auto mfma8 = [&](f32x4* a, const bf16x8* w) {
        #pragma unroll
        for (int ks = 0; ks < 4; ks++) {
            a[0] = __builtin_amdgcn_mfma_f32_16x16x32_bf16(w[ks], bfrag2[0][ks], a[0], 0, 0, 0);
            a[1] = __builtin_amdgcn_mfma_f32_16x16x32_bf16(w[ks], bfrag2[1][ks], a[1], 0, 0, 0);
        }
    };
    #pragma unroll
    for (int g = 0; g < 2; g++) {
        f32x4 acc[4][2];
        #pragma unroll
        for (int t = 0; t < 4; t++) {
            const float4 bi = *(const float4*)(bb1 + (wave * 8 + g * 4 + t) * 16 + quad * 4);
            acc[t][0] = (f32x4){ bi.x, bi.y, bi.z, bi.w };
            acc[t][1] = acc[t][0];
        }
        bf16x8 wA[4], wB[4];
        loadw1(wA, g * 4 + 0);
        loadw1(wB, g * 4 + 1);
        mfma8(acc[0], wA);
        loadw1(wA, g * 4 + 2);
        mfma8(acc[1], wB);
        loadw1(wB, g * 4 + 3);
        mfma8(acc[2], wA);
        mfma8(acc[3], wB);
        #pragma unroll
        for (int t = 0; t < 4; t++) {
            const int nb = (wave * 8 + g * 4 + t) * 16 + quad * 4;
            #pragma unroll
            for (int mt = 0; mt < 2; mt++) {
                short4v p;
                #pragma unroll
                for (int i = 0; i < 4; i++) {
                    const float a = acc[t][mt][i];
                    p[i] = f2bs(0.5f * a * (1.f + erff(a * 0.70710678118f)));
                }
                *(short4v*)&H_s[(mt * 16 + l16) * kHP + nb] = p;
            }
        }
    }
    __syncthreads();    // sync5: H_s ready

    // ================= Phase D: fc2 + final write (Xo + mlp) ===============
    const int ct0 = wave * 2;
    f32x4 acc2[2][2];
    #pragma unroll
    for (int t = 0; t < 2; t++) {
        const float4 bi = *(const float4*)(bb2 + (ct0 + t) * 16 + quad * 4);
        acc2[t][0] = (f32x4){ bi.x, bi.y, bi.z, bi.w };
        acc2[t][1] = acc2[t][0];
    }
    const short* w2base = w2b + (size_t)(ct0 * 16 + l16) * kMLP + quad * 8;
    const short* hbase0 = &H_s[l16 * kHP + quad * 8];
    const short* hbase1 = &H_s[(16 + l16) * kHP + quad * 8];
    auto loadh = [&](bf16x8* h, bf16x8* w, int kk) {
        h[0] = *(const bf16x8*)(hbase0 + kk * 32);
        h[1] = *(const bf16x8*)(hbase1 + kk * 32);
        w[0] = *(const bf16x8*)(w2base + kk * 32);
        w[1] = *(const bf16x8*)(w2base + (size_t)16 * kMLP + kk * 32);
    };
    auto mfma4 = [&](const bf16x8* h, const bf16x8* w) {
        acc2[0][0] = __builtin_amdgcn_mfma_f32_16x16x32_bf16(w[0], h[0], acc2[0][0], 0, 0, 0);
        acc2[0][1] = __builtin_amdgcn_mfma_f32_16x16x32_bf16(w[0], h[1], acc2[0][1], 0, 0, 0);
        acc2[1][0] = __builtin_amdgcn_mfma_f32_16x16x32_bf16(w[1], h[0], acc2[1][0], 0, 0, 0);
        acc2[1][1] = __builtin_amdgcn_mfma_f32_16x16x32_bf16(w[1], h[1], acc2[1][1], 0, 0, 0);
    };
    bf16x8 hA[2], wwA[2], hB[2], wwB[2];
    loadh(hA, wwA, 0);
    #pragma unroll
    for (int kk = 0; kk < 16; kk += 2) {
        loadh(hB, wwB, kk + 1);
        mfma4(hA, wwA);
        if (kk + 2 < 16) loadh(hA, wwA, kk + 2);
        mfma4(hB, wwB);
    }

    #pragma unroll
    for (int t = 0; t < 2; t++) {
        const int cbv = (ct0 + t) * 16 + quad * 4;
        #pragma unroll
        for (int mt = 0; mt < 2; mt++) {
            const size_t m = row0 + mt * 16 + l16;
            const float4 xo = *(const float4*)&Xo[(mt * 16 + l16) * kXP + cbv];
            float4 r;
            r.x = xo.x + acc2[t][mt][0]; r.y = xo.y + acc2[t][mt][1];
            r.z = xo.z + acc2[t][mt][2]; r.w = xo.w + acc2[t][mt][3];
            *(float4*)(out + m * kC + cbv) = r;
        }
    }
}

// ---------------------------------------------------------------------------
extern "C" void kernel_launch(void* const* d_in, const int* in_sizes, int n_in,
                              void* d_out, int out_size, void* d_ws, size_t ws_size,
                              hipStream_t stream) {
    (void)in_sizes; (void)n_in; (void)out_size; (void)ws_size;
    const float* x      = (const float*)d_in[0];
    const float* v      = (const float*)d_in[1];
    const float* n1g    = (const float*)d_in[2];
    const float* n1b    = (const float*)d_in[3];
    const float* nvg    = (const float*)d_in[4];
    const float* nvb    = (const float*)d_in[5];
    const float* q_w    = (const float*)d_in[6];
    const float* q_b    = (const float*)d_in[7];
    const float* kv_w   = (const float*)d_in[8];
    const float* kv_b   = (const float*)d_in[9];
    const float* rpb    = (const float*)d_in[10];
    const float* proj_w = (const float*)d_in[11];
    const float* proj_b = (const float*)d_in[12];
    const float* n2g    = (const float*)d_in[13];
    const float* n2b    = (const float*)d_in[14];
    const float* fc1_w  = (const float*)d_in[15];
    const float* fc1_b  = (const float*)d_in[16];
    const float* fc2_w  = (const float*)d_in[17];
    const float* fc2_b  = (const float*)d_in[18];

    const size_t winTot = (size_t)4096 * kWinElems;   // 25,690,112 elems
    bf16* qbuf = (bf16*)d_ws;
    bf16* kbuf = qbuf + winTot;
    bf16* vbuf = kbuf + winTot;                        // 154 MB
    short* wcvt = (short*)(vbuf + winTot);             // bf16 weight arena
    short* qwb  = wcvt;                                // 16384
    short* kvwb = qwb + 16384;                         // 32768
    short* pwb  = kvwb + 32768;                        // 16384
    short* w1b  = pwb + 16384;                         // 65536
    short* w2b  = w1b + 65536;                         // 65536
    float* outb = (float*)d_out;

    k_cvt<<<768, 256, 0, stream>>>(q_w, kv_w, proj_w, fc1_w, fc2_w, wcvt);
    k_ln_qkv_mfma<<<6272, 256, 0, stream>>>(x, v, n1g, n1b, nvg, nvb,
                                            qwb, q_b, kvwb, kv_b, qbuf, kbuf, vbuf);
    k_attn_mfma<<<4096, 256, 0, stream>>>(qbuf, kbuf, vbuf, rpb);
    k_proj_mlp<<<6272, 256, 0, stream>>>(qbuf, pwb, proj_b, x, outb,
                                         n2g, n2b, w1b, fc1_b, w2b, fc2_b);
}